// Round 4
// baseline (131.211 us; speedup 1.0000x reference)
//
#include <hip/hip_runtime.h>
#include <hip/hip_bf16.h>

// CARAFE: B=4, C=128, H=W=64, C_MID=64, S=2, K=5
// Round 14: split the monolith. prep -> K1 (h once, full image) -> K2 (conv+
// softmax, 8x8 tiles) -> K3 (W-scatter + reassembly MFMA, 4x4 tiles).
// Kills: h halo recompute (2.25x), per-block 126KB w2b stream (129MB -> 32MB),
// idle-wave softmax phase, 5-barrier critical path.
#define HW 4096

typedef __attribute__((ext_vector_type(8))) short  short8;   // 8 bf16 (4 VGPRs)
typedef __attribute__((ext_vector_type(4))) float  floatx4;  // MFMA C/D
typedef __attribute__((ext_vector_type(4))) unsigned short ushort4v;

// workspace (BYTE offsets)
#define OFF_W2B 0ul        // bf16 [112][576]  = 129024 B   w2b[n][k], k = tap*64 + c
#define OFF_W1B 129024ul   // bf16 [64][128]   = 16384 B    w1b[o][c]
#define OFF_BN  145408ul   // float2[64]       = 512 B      (inv, add) per o
#define OFF_XG  145920ul   // bf16 [4][16][4096][8] = 4 MB  x transposed: [b][cq][pix][8c]
#define OFF_XPP 4340224ul  // bf16 [512][68][68]    = 4.73 MB zero-padded planar x
#define OFF_HT  9075200ul  // bf16 [4][4096][64]    = 2 MB   h planar [b][pix][c]
#define OFF_KER 11172352ul // f32  [4][4][25][4096] = 6.55 MB softmaxed kernels

__device__ __forceinline__ float bfbits(unsigned u) {
    union { unsigned u; float f; } t; t.u = u; return t.f;
}

// ---------------- prep (r12 verbatim) ----------------
__global__ __launch_bounds__(256) void prep_kernel(const float* __restrict__ x,
                                                   const float* __restrict__ w1,
                                                   const float* __restrict__ w2,
                                                   const float* __restrict__ gamma,
                                                   const float* __restrict__ beta,
                                                   const float* __restrict__ mean,
                                                   const float* __restrict__ var,
                                                   char* __restrict__ ws) {
    int tid = blockIdx.x * 256 + threadIdx.x;
    if (tid < 262144) {
        int pix = tid & 4095;
        int cq  = (tid >> 12) & 15;
        int b   = tid >> 16;
        const float* xp = x + ((size_t)(b * 128 + cq * 8)) * HW + pix;
        union { short8 s; __hip_bfloat16 h[8]; } u;
        #pragma unroll
        for (int cc = 0; cc < 8; ++cc) u.h[cc] = __float2bfloat16(xp[(size_t)cc * HW]);
        *(short8*)((__hip_bfloat16*)(ws + OFF_XG) + (size_t)tid * 8) = u.s;
        return;
    }
    int t2 = tid - 262144;
    if (t2 < 64512) {
        int n = t2 / 576;
        int k = t2 - n * 576;        // k = tap*64 + c
        int t = k >> 6, c = k & 63;
        float v = (n < 100) ? w2[(n * 64 + c) * 9 + t] : 0.f;
        ((__hip_bfloat16*)(ws + OFF_W2B))[t2] = __float2bfloat16(v);
    } else if (t2 < 64512 + 8192) {
        int i = t2 - 64512;
        ((__hip_bfloat16*)(ws + OFF_W1B))[i] = __float2bfloat16(w1[i]);
    } else if (t2 < 64512 + 8192 + 64) {
        int o = t2 - 64512 - 8192;
        float inv = gamma[o] * rsqrtf(var[o] + 1e-5f);
        ((float2*)(ws + OFF_BN))[o] = make_float2(inv, beta[o] - mean[o] * inv);
    } else {
        int t3 = t2 - 72768;          // XPP: zero-padded planar bf16 copy
        if (t3 < 591872) {            // 512 bc * 68 rows * 17 chunks
            int j  = t3 % 17;
            int rr = t3 / 17;         // (b*128+c)*68 + row68
            int row68 = rr - (rr / 68) * 68;
            int bc = rr / 68;
            int gy = row68 - 2;
            const float* xp = x + (size_t)bc * HW + (size_t)gy * 64;
            union { ushort4v u4; __hip_bfloat16 h[4]; } u;
            #pragma unroll
            for (int e = 0; e < 4; ++e) {
                int gx = j * 4 + e - 2;
                float f = 0.f;
                if ((unsigned)gy < 64u && (unsigned)gx < 64u) f = xp[gx];
                u.h[e] = __float2bfloat16(f);
            }
            *(ushort4v*)((__hip_bfloat16*)(ws + OFF_XPP) + (size_t)rr * 68 + j * 4) = u.u4;
        }
    }
}

// ---------------- K1: h = relu(bn(w1 @ x)) full image. M=16384, N=64, K=128 ------------
// 256 blocks x 256 thr (4 waves). Block = (b, 64-pix chunk). Wave = 16 pix.
__global__ __launch_bounds__(256) void k1_hgemm(const char* __restrict__ ws,
                                               char* __restrict__ wso) {
    __shared__ __align__(16) __hip_bfloat16 hb[64 * 72];   // 9216 B, stride 72 (bank-spread)
    int b = blockIdx.x >> 6;
    int blockpix = (blockIdx.x & 63) * 64;
    int tid = threadIdx.x;
    int lane = tid & 63, wave = tid >> 6;
    int q = lane >> 4, m = lane & 15;

    const __hip_bfloat16* xg  = (const __hip_bfloat16*)(ws + OFF_XG) + (size_t)b * 16 * 4096 * 8;
    const __hip_bfloat16* w1b = (const __hip_bfloat16*)(ws + OFF_W1B);
    int pix = blockpix + wave * 16 + m;    // A-row pixel for this lane

    #pragma unroll
    for (int nt = 0; nt < 4; ++nt) {
        int bo = nt * 16 + m;
        float2 bnia = ((const float2*)(ws + OFF_BN))[bo];
        floatx4 acc;
        #pragma unroll
        for (int r = 0; r < 4; ++r) acc[r] = 0.f;
        #pragma unroll
        for (int s = 0; s < 4; ++s) {
            short8 a  = *(const short8*)(xg + ((size_t)((s * 4 + q) * 4096 + pix)) * 8);
            short8 bw = *(const short8*)(w1b + bo * 128 + s * 32 + q * 8);
            acc = __builtin_amdgcn_mfma_f32_16x16x32_bf16(a, bw, acc, 0, 0, 0);
        }
        #pragma unroll
        for (int r = 0; r < 4; ++r) {
            float v = fmaxf(fmaf(acc[r], bnia.x, bnia.y), 0.f);
            hb[(wave * 16 + q * 4 + r) * 72 + bo] = __float2bfloat16(v);
        }
    }
    __syncthreads();

    // coalesced write-out: 8 KB logical -> HT[b][pix][64]
    __hip_bfloat16* ht = (__hip_bfloat16*)(wso + OFF_HT);
    int lrow = tid >> 2, e0 = (tid & 3) * 16;
    __hip_bfloat16* dst = ht + ((size_t)b * 4096 + blockpix + lrow) * 64 + e0;
    *(short8*)(dst)     = *(const short8*)(&hb[lrow * 72 + e0]);
    *(short8*)(dst + 8) = *(const short8*)(&hb[lrow * 72 + e0 + 8]);
}

// ---------------- K2: 3x3 conv -> logits -> softmax -> KER. 8x8 tiles, 256 blocks ------
// M=64 pix, N=112, K=576. 256 thr = 4 waves, wave = mt.
__global__ __launch_bounds__(256) void k2_conv(const char* __restrict__ ws,
                                               char* __restrict__ wso) {
    __shared__ __align__(16) char smem[41984];
    __hip_bfloat16* hs = (__hip_bfloat16*)smem;          // [100 rows][64 c] swizzled, 12800 B
    float*          lg = (float*)(smem + 12800);         // [64 pix][114] f32, 29184 B

    int b = blockIdx.x >> 6;
    int t = blockIdx.x & 63;
    int ty0 = (t >> 3) * 8, tx0 = (t & 7) * 8;
    int tid = threadIdx.x;
    int lane = tid & 63, wave = tid >> 6;
    int q = lane >> 4, m = lane & 15;

    // stage h halo 10x10 rows x 64c from HT (zero pad outside image)
    const __hip_bfloat16* ht = (const __hip_bfloat16*)(ws + OFF_HT);
    #pragma unroll
    for (int it = 0; it < 4; ++it) {
        int idx = it * 256 + tid;
        if (idx < 800) {
            int row = idx >> 3, co = idx & 7;
            int hy = row / 10, hx = row - hy * 10;
            int gy = ty0 + hy - 1, gx = tx0 + hx - 1;
            short8 v;
            #pragma unroll
            for (int j = 0; j < 8; ++j) v[j] = 0;
            if ((unsigned)gy < 64u && (unsigned)gx < 64u)
                v = *(const short8*)(ht + ((size_t)b * 4096 + gy * 64 + gx) * 64 + co * 8);
            *(short8*)(&hs[row * 64 + ((co ^ (row & 7)) << 3)]) = v;
        }
    }
    __syncthreads();

    // conv MFMA: wave = mt (16 pix), loop nt 0..6
    {
        int mt = wave;
        int pixidx = mt * 16 + m;
        int py = pixidx >> 3, px = pixidx & 7;
        const __hip_bfloat16* w2b = (const __hip_bfloat16*)(ws + OFF_W2B);
        for (int nt = 0; nt < 7; ++nt) {
            const __hip_bfloat16* bp = w2b + (size_t)(nt * 16 + m) * 576 + q * 8;
            floatx4 acc;
            #pragma unroll
            for (int r = 0; r < 4; ++r) acc[r] = 0.f;
            short8 bcur = *(const short8*)bp;
            for (int s = 0; s < 18; ++s) {
                int tt = s >> 1, co = (s & 1) * 4 + q;
                int ti = tt / 3, tj = tt - ti * 3;
                int row = (py + ti) * 10 + (px + tj);
                short8 a = *(const short8*)(&hs[row * 64 + ((co ^ (row & 7)) << 3)]);
                short8 bn2 = bcur;
                if (s < 17) bn2 = *(const short8*)(bp + (s + 1) * 32);
                acc = __builtin_amdgcn_mfma_f32_16x16x32_bf16(a, bcur, acc, 0, 0, 0);
                bcur = bn2;
            }
            #pragma unroll
            for (int r = 0; r < 4; ++r)
                lg[(mt * 16 + q * 4 + r) * 114 + nt * 16 + m] = acc[r];
        }
    }
    __syncthreads();

    // softmax: 64 pix x 4 g = 256 threads, 1 each; write KER f32
    {
        int pixloc = tid & 63, g = tid >> 6;
        float v[25];
        #pragma unroll
        for (int wi = 0; wi < 25; ++wi) v[wi] = lg[pixloc * 114 + g * 25 + wi];
        float mx = v[0];
        #pragma unroll
        for (int wi = 1; wi < 25; ++wi) mx = fmaxf(mx, v[wi]);
        float ssum = 0.f;
        #pragma unroll
        for (int wi = 0; wi < 25; ++wi) { v[wi] = __expf(v[wi] - mx); ssum += v[wi]; }
        float rs = 1.f / ssum;
        int gpix = (ty0 + (pixloc >> 3)) * 64 + tx0 + (pixloc & 7);
        float* ker = (float*)(wso + OFF_KER);
        #pragma unroll
        for (int t25 = 0; t25 < 25; ++t25)
            ker[(((size_t)(b * 4 + g) * 25 + t25)) * 4096 + gpix] = v[t25] * rs;
    }
}

// ---------------- K3: W scatter + reassembly MFMA + pixel shuffle. 4x4 tiles ----------
// 1024 blocks x 256 thr (4 waves). LDS: xsT 16KB + Whi/Wlo 16KB = 32768 B.
__global__ __launch_bounds__(256) void k3_reassemble(const char* __restrict__ ws,
                                                     float* __restrict__ out) {
    __shared__ __align__(16) char smem[32768];
    __hip_bfloat16* xsT = (__hip_bfloat16*)smem;                 // [128 c][64 hp] swz
    __hip_bfloat16* Whi = (__hip_bfloat16*)(smem + 16384);       // [64][64] swz; Wlo at +4096

    int b    = blockIdx.x >> 8;
    int tile = blockIdx.x & 255;
    int ty0 = (tile >> 4) * 4;
    int tx0 = (tile & 15) * 4;
    int tid = threadIdx.x;
    int lane = tid & 63, wave = tid >> 6;
    int q = lane >> 4, m = lane & 15;

    // phase 1: stage xsT from XPP + zero W
    const __hip_bfloat16* xpp = (const __hip_bfloat16*)(ws + OFF_XPP);
    #pragma unroll
    for (int it = 0; it < 4; ++it) {
        int idx = it * 256 + tid;             // 1024 = 128 c * 8 h-rows
        int c = idx >> 3, h = idx & 7;
        size_t rb = ((size_t)(b * 128 + c) * 68 + (ty0 + h)) * 68 + tx0;  // 8B aligned
        union { short8 s; uint2 d[2]; } u;
        u.d[0] = *(const uint2*)(xpp + rb);
        u.d[1] = *(const uint2*)(xpp + rb + 4);
        *(short8*)(xsT + c * 64 + ((h ^ (c & 7)) << 3)) = u.s;
    }
    {
        short8 z;
        #pragma unroll
        for (int j = 0; j < 8; ++j) z[j] = 0;
        char* wb = (char*)Whi + tid * 64;
        #pragma unroll
        for (int j = 0; j < 4; ++j) *(short8*)(wb + j * 16) = z;
    }
    __syncthreads();

    // prefetch E B-frags (xsT stable); wave covers c-blocks wave*2, wave*2+1
    short8 eb[2][2];
    int ecs[2];
    #pragma unroll
    for (int ntl = 0; ntl < 2; ++ntl) {
        int c = (wave * 2 + ntl) * 16 + m;
        ecs[ntl] = c;
        const __hip_bfloat16* xr = xsT + c * 64;
        eb[ntl][0] = *(const short8*)(xr + ((q ^ (c & 7)) << 3));
        eb[ntl][1] = *(const short8*)(xr + (((4 + q) ^ (c & 7)) << 3));
    }

    // phase 2: scatter softmaxed ker into W rows (hi + lo bf16)
    {
        const float* ker = (const float*)(ws + OFF_KER);
        int row = tid >> 2, tq = tid & 2 ? (tid & 3) : (tid & 3); // row 0..63
        tq = tid & 3;
        int pixid = row >> 2, g = row & 3;
        int py = pixid >> 2, px = pixid & 3;
        int gpix = (ty0 + py) * 64 + (tx0 + px);
        for (int t25 = tq; t25 < 25; t25 += 4) {
            float kv = ker[(((size_t)(b * 4 + g) * 25 + t25)) * 4096 + gpix];
            int ti = t25 / 5, tj = t25 - ti * 5;
            int addr = row * 64 + ((((py + ti) ^ (row & 7)) << 3) | (px + tj));
            __hip_bfloat16 khi = __float2bfloat16(kv);
            Whi[addr] = khi;
            Whi[4096 + addr] = __float2bfloat16(kv - __bfloat162float(khi));
        }
    }
    __syncthreads();

    // phase 3: out[64 pixg][128 c] = (Whi+Wlo)[64x64] @ X[64x128]
    #pragma unroll
    for (int mt = 0; mt < 4; ++mt) {
        int row = mt * 16 + m;
        const __hip_bfloat16* wr = Whi + row * 64;
        int s0 = ((q ^ (row & 7)) << 3);
        int s1 = (((4 + q) ^ (row & 7)) << 3);
        short8 ah0 = *(const short8*)(wr + s0);
        short8 al0 = *(const short8*)(wr + 4096 + s0);
        short8 ah1 = *(const short8*)(wr + s1);
        short8 al1 = *(const short8*)(wr + 4096 + s1);
        #pragma unroll
        for (int ntl = 0; ntl < 2; ++ntl) {
            floatx4 acc;
            #pragma unroll
            for (int r = 0; r < 4; ++r) acc[r] = 0.f;
            acc = __builtin_amdgcn_mfma_f32_16x16x32_bf16(ah0, eb[ntl][0], acc, 0, 0, 0);
            acc = __builtin_amdgcn_mfma_f32_16x16x32_bf16(al0, eb[ntl][0], acc, 0, 0, 0);
            acc = __builtin_amdgcn_mfma_f32_16x16x32_bf16(ah1, eb[ntl][1], acc, 0, 0, 0);
            acc = __builtin_amdgcn_mfma_f32_16x16x32_bf16(al1, eb[ntl][1], acc, 0, 0, 0);
            float* op = out + (((size_t)b * 128 + ecs[ntl]) << 14)
                      + (size_t)(2 * (ty0 + mt)) * 128 + 2 * (tx0 + q);
            *(float2*)op         = make_float2(acc[0], acc[1]);   // gy=0: gx=0,1
            *(float2*)(op + 128) = make_float2(acc[2], acc[3]);   // gy=1: gx=0,1
        }
    }
}

extern "C" void kernel_launch(void* const* d_in, const int* in_sizes, int n_in,
                              void* d_out, int out_size, void* d_ws, size_t ws_size,
                              hipStream_t stream) {
    const float* x     = (const float*)d_in[0];
    const float* w1    = (const float*)d_in[1];
    const float* w2    = (const float*)d_in[2];
    const float* gamma = (const float*)d_in[3];
    const float* beta  = (const float*)d_in[4];
    const float* mean  = (const float*)d_in[5];
    const float* var   = (const float*)d_in[6];
    float* out = (float*)d_out;
    char*  ws  = (char*)d_ws;

    prep_kernel<<<3621, 256, 0, stream>>>(x, w1, w2, gamma, beta, mean, var, ws);
    k1_hgemm<<<256, 256, 0, stream>>>(ws, ws);
    k2_conv<<<256, 256, 0, stream>>>(ws, ws);
    k3_reassemble<<<1024, 256, 0, stream>>>(ws, out);
}

// Round 5
// 116.335 us; speedup vs baseline: 1.1279x; 1.1279x over previous
//
#include <hip/hip_runtime.h>
#include <hip/hip_bf16.h>

// CARAFE fused: B=4, C=128, H=W=64, C_MID=64, S=2, K=5
// Round 15: r12 monolith + three surgical fixes:
//  (1) phase E computes out^T: D=[c][pixg] (operand swap) -> stores become
//      2x32B contiguous segments instead of 8B plane-scatter (write-BW fix).
//  (2) wave-parallel softmax+scatter (512 thr, shfl_xor-8) replaces 64-thr D2.
//  (3) __launch_bounds__(512,4) (r12's (512,8) forced VGPR=24).
// prep / phase A / B / C / D1 / LDS map identical to r12 (passing, absmax 0.0078).
#define HW 4096

typedef __attribute__((ext_vector_type(8))) short  short8;   // 8 bf16 (4 VGPRs)
typedef __attribute__((ext_vector_type(4))) float  floatx4;  // MFMA C/D
typedef __attribute__((ext_vector_type(4))) unsigned short ushort4v;

// workspace (BYTE offsets)
#define OFF_W2B 0ul        // bf16 [112][576]  = 129024 B   w2b[n][k], k = tap*64 + c
#define OFF_W1B 129024ul   // bf16 [64][128]   = 16384 B    w1b[o][c]
#define OFF_BN  145408ul   // float2[64]       = 512 B      (inv, add) per o
#define OFF_XG  145920ul   // bf16 [4][16][4096][8] = 4 MB  x transposed: [b][cq][pix][8c]
#define OFF_XPP 4340224ul  // bf16 [512][68][68]    = 4.73 MB zero-padded planar x

// ---------------- prep (r12 verbatim) ----------------
__global__ __launch_bounds__(256) void prep_kernel(const float* __restrict__ x,
                                                   const float* __restrict__ w1,
                                                   const float* __restrict__ w2,
                                                   const float* __restrict__ gamma,
                                                   const float* __restrict__ beta,
                                                   const float* __restrict__ mean,
                                                   const float* __restrict__ var,
                                                   char* __restrict__ ws) {
    int tid = blockIdx.x * 256 + threadIdx.x;
    if (tid < 262144) {
        int pix = tid & 4095;
        int cq  = (tid >> 12) & 15;
        int b   = tid >> 16;
        const float* xp = x + ((size_t)(b * 128 + cq * 8)) * HW + pix;
        union { short8 s; __hip_bfloat16 h[8]; } u;
        #pragma unroll
        for (int cc = 0; cc < 8; ++cc) u.h[cc] = __float2bfloat16(xp[(size_t)cc * HW]);
        *(short8*)((__hip_bfloat16*)(ws + OFF_XG) + (size_t)tid * 8) = u.s;
        return;
    }
    int t2 = tid - 262144;
    if (t2 < 64512) {
        int n = t2 / 576;
        int k = t2 - n * 576;        // k = tap*64 + c
        int t = k >> 6, c = k & 63;
        float v = (n < 100) ? w2[(n * 64 + c) * 9 + t] : 0.f;
        ((__hip_bfloat16*)(ws + OFF_W2B))[t2] = __float2bfloat16(v);
    } else if (t2 < 64512 + 8192) {
        int i = t2 - 64512;
        ((__hip_bfloat16*)(ws + OFF_W1B))[i] = __float2bfloat16(w1[i]);
    } else if (t2 < 64512 + 8192 + 64) {
        int o = t2 - 64512 - 8192;
        float inv = gamma[o] * rsqrtf(var[o] + 1e-5f);
        ((float2*)(ws + OFF_BN))[o] = make_float2(inv, beta[o] - mean[o] * inv);
    } else {
        int t3 = t2 - 72768;          // XPP: zero-padded planar bf16 copy
        if (t3 < 591872) {            // 512 bc * 68 rows * 17 chunks
            int j  = t3 % 17;
            int rr = t3 / 17;         // (b*128+c)*68 + row68
            int row68 = rr - (rr / 68) * 68;
            int bc = rr / 68;
            int gy = row68 - 2;
            const float* xp = x + (size_t)bc * HW + (size_t)gy * 64;
            union { ushort4v u4; __hip_bfloat16 h[4]; } u;
            #pragma unroll
            for (int e = 0; e < 4; ++e) {
                int gx = j * 4 + e - 2;
                float f = 0.f;
                if ((unsigned)gy < 64u && (unsigned)gx < 64u) f = xp[gx];
                u.h[e] = __float2bfloat16(f);
            }
            *(ushort4v*)((__hip_bfloat16*)(ws + OFF_XPP) + (size_t)rr * 68 + j * 4) = u.u4;
        }
    }
}

// ---------------- fused CARAFE: one block per (b, 4x4 tile), 512 threads = 8 waves ----------
// LDS (40,064 B):
//   xsT [128 c][64 hp] bf16 swz  @ 0      (16384)  live A..E
//   lg  [16 pix][114]  f32       @ 16384  ( 7296)  live C..D
//   hs  [36 pix][64 c] bf16 swz  @ 23680  ( 4608)  live B..C } aliased pool (16384)
//   Whi/Wlo [64][64]  bf16 swz   @ 23680  (16384)  live D..E }
__global__ __launch_bounds__(512, 4) void fused_carafe(const char* __restrict__ ws,
                                                       float* __restrict__ out) {
    __shared__ __align__(16) char smem[40064];
    __hip_bfloat16* xsT = (__hip_bfloat16*)smem;
    float*          lg  = (float*)(smem + 16384);
    __hip_bfloat16* hs  = (__hip_bfloat16*)(smem + 23680);
    __hip_bfloat16* Whi = (__hip_bfloat16*)(smem + 23680);   // Wlo = Whi + 4096 elems

    int b    = blockIdx.x >> 8;
    int tile = blockIdx.x & 255;
    int ty0 = (tile >> 4) * 4;
    int tx0 = (tile & 15) * 4;
    int tid = threadIdx.x;
    int lane = tid & 63, wave = tid >> 6;   // 8 waves
    int q = lane >> 4, m = lane & 15;

    // ---- phase A: stage xsT[c][hp] from padded planar XPP; chunk-XOR swizzle ----
    const __hip_bfloat16* xpp = (const __hip_bfloat16*)(ws + OFF_XPP);
    #pragma unroll
    for (int it = 0; it < 2; ++it) {
        int idx = tid + it * 512;             // 1024 = 128 c * 8 h-rows
        int c = idx >> 3, h = idx & 7;
        size_t rb = ((size_t)(b * 128 + c) * 68 + (ty0 + h)) * 68 + tx0;  // 8B aligned
        union { short8 s; uint2 d[2]; } u;
        u.d[0] = *(const uint2*)(xpp + rb);
        u.d[1] = *(const uint2*)(xpp + rb + 4);
        *(short8*)(xsT + c * 64 + ((h ^ (c & 7)) << 3)) = u.s;
    }

    // ---- phase B: h = relu(bn(w1 @ x)); M=36 halo pix (6x6), N=64, K=128 ----
    // A-frags straight from L2 (XG layout); 12 tasks (3 mt x 4 nt) over 8 waves
    {
        const __hip_bfloat16* xg  = (const __hip_bfloat16*)(ws + OFF_XG) + (size_t)b * 16 * 4096 * 8;
        const __hip_bfloat16* w1b = (const __hip_bfloat16*)(ws + OFF_W1B);
        for (int task = wave; task < 12; task += 8) {
            int mt = task >> 2, nt = task & 3;
            int bo = nt * 16 + m;
            float2 bnia = ((const float2*)(ws + OFF_BN))[bo];
            int hp = mt * 16 + m;
            int hpc = (hp < 36) ? hp : 0;          // clamp dead A-rows (C rows discarded)
            int hy1 = hpc / 6, hx1 = hpc - hy1 * 6;
            int gy = ty0 + hy1 - 1, gx = tx0 + hx1 - 1;
            int gyc = min(max(gy, 0), 63), gxc = min(max(gx, 0), 63);
            int pix = gyc * 64 + gxc;
            floatx4 acc;
            #pragma unroll
            for (int r = 0; r < 4; ++r) acc[r] = 0.f;
            #pragma unroll
            for (int s = 0; s < 4; ++s) {
                short8 a  = *(const short8*)(xg + ((size_t)((s * 4 + q) * 4096 + pix)) * 8);
                short8 bw = *(const short8*)(w1b + bo * 128 + s * 32 + q * 8);
                acc = __builtin_amdgcn_mfma_f32_16x16x32_bf16(a, bw, acc, 0, 0, 0);
            }
            #pragma unroll
            for (int r = 0; r < 4; ++r) {
                int prow = mt * 16 + q * 4 + r;
                if (prow < 36) {
                    int phy = prow / 6, phx = prow - phy * 6;
                    int gy2 = ty0 + phy - 1, gx2 = tx0 + phx - 1;
                    bool in = ((unsigned)gy2 < 64u) && ((unsigned)gx2 < 64u);
                    float v = in ? fmaxf(fmaf(acc[r], bnia.x, bnia.y), 0.f) : 0.f;
                    hs[prow * 64 + ((((bo >> 3) ^ (prow & 7)) << 3) | (bo & 7))] = __float2bfloat16(v);
                }
            }
        }
    }
    __syncthreads();

    // ---- phase C: 3x3 conv via MFMA: M=16 pix, N=112, K=576; 7 n-tile tasks ----
    if (wave < 7) {
        int nt = wave;
        int py = m >> 2, px = m & 3;
        const __hip_bfloat16* w2b = (const __hip_bfloat16*)(ws + OFF_W2B);
        const __hip_bfloat16* bp  = w2b + (size_t)(nt * 16 + m) * 576 + q * 8;

        floatx4 acc;
        #pragma unroll
        for (int r = 0; r < 4; ++r) acc[r] = 0.f;

        short8 bcur = *(const short8*)bp;
        for (int s = 0; s < 18; ++s) {
            int t = s >> 1, co = (s & 1) * 4 + q;      // c-oct index 0..7
            int ti = t / 3, tj = t - ti * 3;
            int row = (py + ti) * 6 + (px + tj);
            short8 a = *(const short8*)(hs + row * 64 + ((co ^ (row & 7)) << 3));
            short8 bn2 = bcur;
            if (s < 17) bn2 = *(const short8*)(bp + (s + 1) * 32);
            acc = __builtin_amdgcn_mfma_f32_16x16x32_bf16(a, bcur, acc, 0, 0, 0);
            bcur = bn2;
        }
        #pragma unroll
        for (int r = 0; r < 4; ++r)
            lg[(q * 4 + r) * 114 + nt * 16 + m] = acc[r];
    }
    __syncthreads();

    // ---- phase D1: zero Whi/Wlo (aliases hs, now dead) ----
    {
        short8 z;
        #pragma unroll
        for (int j = 0; j < 8; ++j) z[j] = 0;
        *(short8*)((char*)Whi + tid * 16) = z;          // 512*16 = 8192 = Whi
        *(short8*)((char*)Whi + 8192 + tid * 16) = z;   // Wlo
    }
    __syncthreads();

    // ---- phase D2: wave-parallel softmax over 25 taps -> scatter W rows (hi+lo bf16) ----
    // 512 threads: 64 rows x 8 subthreads; shfl_xor reduction within aligned 8-groups.
    {
        int row = tid >> 3;                 // pixg row 0..63
        int sub = tid & 7;
        int pixid = row >> 2, g = row & 3;
        int py = pixid >> 2, px = pixid & 3;
        float v[4];
        float mx = -1e30f;
        #pragma unroll
        for (int k = 0; k < 4; ++k) {
            int t25 = sub + k * 8;
            v[k] = (t25 < 25) ? lg[pixid * 114 + g * 25 + t25] : -1e30f;
            mx = fmaxf(mx, v[k]);
        }
        #pragma unroll
        for (int d = 1; d < 8; d <<= 1) mx = fmaxf(mx, __shfl_xor(mx, d, 64));
        float ssum = 0.f;
        #pragma unroll
        for (int k = 0; k < 4; ++k) { v[k] = __expf(v[k] - mx); ssum += v[k]; }
        #pragma unroll
        for (int d = 1; d < 8; d <<= 1) ssum += __shfl_xor(ssum, d, 64);
        float rs = 1.f / ssum;
        #pragma unroll
        for (int k = 0; k < 4; ++k) {
            int t25 = sub + k * 8;
            if (t25 < 25) {
                int ti = t25 / 5, tj = t25 - ti * 5;
                int addr = row * 64 + ((((py + ti) ^ (row & 7)) << 3) | (px + tj));
                float kv = v[k] * rs;
                __hip_bfloat16 khi = __float2bfloat16(kv);
                Whi[addr] = khi;
                Whi[4096 + addr] = __float2bfloat16(kv - __bfloat162float(khi));
            }
        }
    }
    __syncthreads();

    // ---- phase E: out^T[c][pixg] = X[c x hp] @ W^T[hp x pixg]  (orientation-1) ----
    // wave: pt = wave&3 (pixg 16-tile), ch = wave>>2 (c 64-half); ct loop 0..3.
    // Store: m-lanes span 16 consecutive pixg -> 2 rows x 32B contiguous per store.
    {
        int pt = wave & 3, ch = wave >> 2;
        int browW = pt * 16 + m;                       // W row = pixg (B-operand cols)
        const __hip_bfloat16* wr = Whi + browW * 64;
        int s0 = ((q ^ (browW & 7)) << 3);
        int s1 = (((4 + q) ^ (browW & 7)) << 3);
        short8 bh0 = *(const short8*)(wr + s0);
        short8 bl0 = *(const short8*)(wr + 4096 + s0);
        short8 bh1 = *(const short8*)(wr + s1);
        short8 bl1 = *(const short8*)(wr + 4096 + s1);

        // per-lane output position from pixg = pt*16 + m
        int px = m >> 2;                               // pix = pt*4 + px (py = pt)
        int gy = (m >> 1) & 1, gx = m & 1;
        size_t rowoff = (size_t)(2 * (ty0 + pt) + gy) * 128 + 2 * (tx0 + px) + gx;

        #pragma unroll
        for (int ct = 0; ct < 4; ++ct) {
            int ca = ch * 64 + ct * 16 + m;            // A-operand row = channel
            const __hip_bfloat16* xr = xsT + ca * 64;
            short8 a0 = *(const short8*)(xr + ((q ^ (ca & 7)) << 3));
            short8 a1 = *(const short8*)(xr + (((4 + q) ^ (ca & 7)) << 3));
            floatx4 acc;
            #pragma unroll
            for (int r = 0; r < 4; ++r) acc[r] = 0.f;
            acc = __builtin_amdgcn_mfma_f32_16x16x32_bf16(a0, bh0, acc, 0, 0, 0);
            acc = __builtin_amdgcn_mfma_f32_16x16x32_bf16(a0, bl0, acc, 0, 0, 0);
            acc = __builtin_amdgcn_mfma_f32_16x16x32_bf16(a1, bh1, acc, 0, 0, 0);
            acc = __builtin_amdgcn_mfma_f32_16x16x32_bf16(a1, bl1, acc, 0, 0, 0);
            int cbase = ch * 64 + ct * 16 + q * 4;     // D row = channel
            #pragma unroll
            for (int r = 0; r < 4; ++r)
                out[(((size_t)(b * 128 + cbase + r)) << 14) + rowoff] = acc[r];
        }
    }
}

extern "C" void kernel_launch(void* const* d_in, const int* in_sizes, int n_in,
                              void* d_out, int out_size, void* d_ws, size_t ws_size,
                              hipStream_t stream) {
    const float* x     = (const float*)d_in[0];
    const float* w1    = (const float*)d_in[1];
    const float* w2    = (const float*)d_in[2];
    const float* gamma = (const float*)d_in[3];
    const float* beta  = (const float*)d_in[4];
    const float* mean  = (const float*)d_in[5];
    const float* var   = (const float*)d_in[6];
    float* out = (float*)d_out;
    char*  ws  = (char*)d_ws;

    prep_kernel<<<3621, 256, 0, stream>>>(x, w1, w2, gamma, beta, mean, var, ws);
    fused_carafe<<<1024, 512, 0, stream>>>(ws, out);
}

// Round 6
// 114.795 us; speedup vs baseline: 1.1430x; 1.0134x over previous
//
#include <hip/hip_runtime.h>
#include <hip/hip_bf16.h>

// CARAFE fused: B=4, C=128, H=W=64, C_MID=64, S=2, K=5
// Round 16: r10 geometry (4x8 tile, 512 blocks, 2 blocks/CU) + all proven fixes:
//   - MFMA reassembly (r12) as TWO 4x4 subproblems, both W (hi/lo) resident
//   - out^T contiguous stores (r15)
//   - wave-parallel softmax (r15)
//   - swizzled hs (r12); xsT [c][8r][12col] stride-100 (bank-spread, subtile-
//     contiguous B-frags)
// LDS 72,960 B: xsT 25.6K | lg 14.6K | Wpool 32K (aliases hs 7.7K). 4 barriers.
#define HW 4096
#define XSTR 100

typedef __attribute__((ext_vector_type(8))) short  short8;   // 8 bf16 (4 VGPRs)
typedef __attribute__((ext_vector_type(4))) float  floatx4;  // MFMA C/D
typedef __attribute__((ext_vector_type(4))) unsigned short ushort4v;

// workspace (BYTE offsets)
#define OFF_W2B 0ul        // bf16 [112][576]  = 129024 B   w2b[n][k], k = tap*64 + c
#define OFF_W1B 129024ul   // bf16 [64][128]   = 16384 B    w1b[o][c]
#define OFF_BN  145408ul   // float2[64]       = 512 B      (inv, add) per o
#define OFF_XG  145920ul   // bf16 [4][16][4096][8] = 4 MB  x transposed: [b][cq][pix][8c]
#define OFF_XPP 4340224ul  // bf16 [512][68][68]    = 4.73 MB zero-padded planar x

// ---------------- prep (r12 verbatim) ----------------
__global__ __launch_bounds__(256) void prep_kernel(const float* __restrict__ x,
                                                   const float* __restrict__ w1,
                                                   const float* __restrict__ w2,
                                                   const float* __restrict__ gamma,
                                                   const float* __restrict__ beta,
                                                   const float* __restrict__ mean,
                                                   const float* __restrict__ var,
                                                   char* __restrict__ ws) {
    int tid = blockIdx.x * 256 + threadIdx.x;
    if (tid < 262144) {
        int pix = tid & 4095;
        int cq  = (tid >> 12) & 15;
        int b   = tid >> 16;
        const float* xp = x + ((size_t)(b * 128 + cq * 8)) * HW + pix;
        union { short8 s; __hip_bfloat16 h[8]; } u;
        #pragma unroll
        for (int cc = 0; cc < 8; ++cc) u.h[cc] = __float2bfloat16(xp[(size_t)cc * HW]);
        *(short8*)((__hip_bfloat16*)(ws + OFF_XG) + (size_t)tid * 8) = u.s;
        return;
    }
    int t2 = tid - 262144;
    if (t2 < 64512) {
        int n = t2 / 576;
        int k = t2 - n * 576;        // k = tap*64 + c
        int t = k >> 6, c = k & 63;
        float v = (n < 100) ? w2[(n * 64 + c) * 9 + t] : 0.f;
        ((__hip_bfloat16*)(ws + OFF_W2B))[t2] = __float2bfloat16(v);
    } else if (t2 < 64512 + 8192) {
        int i = t2 - 64512;
        ((__hip_bfloat16*)(ws + OFF_W1B))[i] = __float2bfloat16(w1[i]);
    } else if (t2 < 64512 + 8192 + 64) {
        int o = t2 - 64512 - 8192;
        float inv = gamma[o] * rsqrtf(var[o] + 1e-5f);
        ((float2*)(ws + OFF_BN))[o] = make_float2(inv, beta[o] - mean[o] * inv);
    } else {
        int t3 = t2 - 72768;          // XPP: zero-padded planar bf16 copy
        if (t3 < 591872) {            // 512 bc * 68 rows * 17 chunks
            int j  = t3 % 17;
            int rr = t3 / 17;         // (b*128+c)*68 + row68
            int row68 = rr - (rr / 68) * 68;
            int bc = rr / 68;
            int gy = row68 - 2;
            const float* xp = x + (size_t)bc * HW + (size_t)gy * 64;
            union { ushort4v u4; __hip_bfloat16 h[4]; } u;
            #pragma unroll
            for (int e = 0; e < 4; ++e) {
                int gx = j * 4 + e - 2;
                float f = 0.f;
                if ((unsigned)gy < 64u && (unsigned)gx < 64u) f = xp[gx];
                u.h[e] = __float2bfloat16(f);
            }
            *(ushort4v*)((__hip_bfloat16*)(ws + OFF_XPP) + (size_t)rr * 68 + j * 4) = u.u4;
        }
    }
}

// ---------------- fused CARAFE: one block per (b, 4x8 tile), 512 threads = 8 waves ----------
// LDS (72,960 B):
//   xsT [128 c][8 rows][12 cols] bf16, row-stride XSTR=100  @ 0      (25,600)  live A..E
//   lg  [32 pix][114] f32                                   @ 25600  (14,592)  live C..D
//   Wpool: hs [60 rows][64 c] swz (7,680, live B..C) ALIAS
//          W  [2 sub][hi/lo][64][64] swz (32,768, live D..E) @ 40192 (32,768)
__global__ __launch_bounds__(512, 4) void fused_carafe(const char* __restrict__ ws,
                                                       float* __restrict__ out) {
    __shared__ __align__(16) char smem[72960];
    __hip_bfloat16* xsT = (__hip_bfloat16*)smem;
    float*          lg  = (float*)(smem + 25600);
    __hip_bfloat16* hs  = (__hip_bfloat16*)(smem + 40192);
    __hip_bfloat16* whp = (__hip_bfloat16*)(smem + 40192);   // [s*8192 + (hi:0/lo:4096) + row*64]

    int b    = blockIdx.x >> 7;
    int tile = blockIdx.x & 127;
    int ty0 = (tile >> 3) * 4;      // 16 tile-rows
    int tx0 = (tile & 7) * 8;       // 8 tile-cols
    int tid = threadIdx.x;
    int lane = tid & 63, wave = tid >> 6;   // 8 waves
    int q = lane >> 4, m = lane & 15;

    // ---- phase A: stage xsT[c][row][col] (8x12 halo) from padded planar XPP ----
    {
        const __hip_bfloat16* xpp = (const __hip_bfloat16*)(ws + OFF_XPP);
        #pragma unroll
        for (int it = 0; it < 2; ++it) {
            int idx = tid + it * 512;             // 1024 = 128 c * 8 rows
            int c = idx >> 3, row = idx & 7;
            const __hip_bfloat16* src = xpp + (size_t)(b * 128 + c) * 4624
                                      + (size_t)(ty0 + row) * 68 + tx0;
            uint2 d0 = *(const uint2*)(src);
            uint2 d1 = *(const uint2*)(src + 4);
            uint2 d2 = *(const uint2*)(src + 8);
            __hip_bfloat16* dst = xsT + c * XSTR + row * 12;
            *(uint2*)(dst)     = d0;
            *(uint2*)(dst + 4) = d1;
            *(uint2*)(dst + 8) = d2;
        }
    }

    // ---- phase B: h = relu(bn(w1 @ x)); M=60 halo pix (6x10), N=64, K=128 ----
    // A-frags from L2 (XG); 16 tasks (4 mt x 4 nt) over 8 waves
    {
        const __hip_bfloat16* xg  = (const __hip_bfloat16*)(ws + OFF_XG) + (size_t)b * 16 * 4096 * 8;
        const __hip_bfloat16* w1b = (const __hip_bfloat16*)(ws + OFF_W1B);
        for (int task = wave; task < 16; task += 8) {
            int mt = task >> 2, nt = task & 3;
            int bo = nt * 16 + m;
            float2 bnia = ((const float2*)(ws + OFF_BN))[bo];
            int hp = mt * 16 + m;
            int hpc = (hp < 60) ? hp : 0;          // clamp dead A-rows
            int hy1 = hpc / 10, hx1 = hpc - hy1 * 10;
            int gy = ty0 + hy1 - 1, gx = tx0 + hx1 - 1;
            int gyc = min(max(gy, 0), 63), gxc = min(max(gx, 0), 63);
            int pix = gyc * 64 + gxc;
            floatx4 acc;
            #pragma unroll
            for (int r = 0; r < 4; ++r) acc[r] = 0.f;
            #pragma unroll
            for (int s = 0; s < 4; ++s) {
                short8 a  = *(const short8*)(xg + ((size_t)((s * 4 + q) * 4096 + pix)) * 8);
                short8 bw = *(const short8*)(w1b + bo * 128 + s * 32 + q * 8);
                acc = __builtin_amdgcn_mfma_f32_16x16x32_bf16(a, bw, acc, 0, 0, 0);
            }
            #pragma unroll
            for (int r = 0; r < 4; ++r) {
                int prow = mt * 16 + q * 4 + r;
                if (prow < 60) {
                    int phy = prow / 10, phx = prow - phy * 10;
                    int gy2 = ty0 + phy - 1, gx2 = tx0 + phx - 1;
                    bool in = ((unsigned)gy2 < 64u) && ((unsigned)gx2 < 64u);
                    float v = in ? fmaxf(fmaf(acc[r], bnia.x, bnia.y), 0.f) : 0.f;
                    hs[prow * 64 + ((((bo >> 3) ^ (prow & 7)) << 3) | (bo & 7))] = __float2bfloat16(v);
                }
            }
        }
    }
    __syncthreads();

    // ---- phase C: 3x3 conv via MFMA: M=32 pix, N=112, K=576; 14 tasks ----
    {
        const __hip_bfloat16* w2b = (const __hip_bfloat16*)(ws + OFF_W2B);
        for (int task = wave; task < 14; task += 8) {
            int mt = task & 1, nt = task >> 1;
            int pixidx = mt * 16 + m;
            int py = pixidx >> 3, px = pixidx & 7;
            const __hip_bfloat16* bp = w2b + (size_t)(nt * 16 + m) * 576 + q * 8;

            floatx4 acc;
            #pragma unroll
            for (int r = 0; r < 4; ++r) acc[r] = 0.f;

            short8 bcur = *(const short8*)bp;
            for (int s = 0; s < 18; ++s) {
                int t = s >> 1, co = (s & 1) * 4 + q;      // c-oct index 0..7
                int ti = t / 3, tj = t - ti * 3;
                int row = (py + ti) * 10 + (px + tj);
                short8 a = *(const short8*)(hs + row * 64 + ((co ^ (row & 7)) << 3));
                short8 bn2 = bcur;
                if (s < 17) bn2 = *(const short8*)(bp + (s + 1) * 32);
                acc = __builtin_amdgcn_mfma_f32_16x16x32_bf16(a, bcur, acc, 0, 0, 0);
                bcur = bn2;
            }
            #pragma unroll
            for (int r = 0; r < 4; ++r)
                lg[(mt * 16 + q * 4 + r) * 114 + nt * 16 + m] = acc[r];
        }
    }
    __syncthreads();

    // ---- phase D1: zero Wpool (aliases hs, now dead) ----
    {
        short8 z;
        #pragma unroll
        for (int j = 0; j < 8; ++j) z[j] = 0;
        char* wb = (char*)whp + tid * 64;                  // 512*64 = 32768
        #pragma unroll
        for (int j = 0; j < 4; ++j) *(short8*)(wb + j * 16) = z;
    }
    __syncthreads();

    // ---- phase D2: wave-parallel softmax (128 rows x 4 subs) -> scatter W hi/lo ----
    {
        int row = tid >> 2, sub = tid & 3;                 // row = pixg 0..127
        int pixid = row >> 2, g = row & 3;
        int py = pixid >> 3, px = pixid & 7;
        int s = px >> 2, pxl = px & 3;
        int wrow = ((py << 2) | pxl) * 4 + g;              // row in subtile-W
        float v[7];
        float mx = -1e30f;
        #pragma unroll
        for (int k = 0; k < 7; ++k) {
            int t25 = sub + k * 4;
            v[k] = (t25 < 25) ? lg[pixid * 114 + g * 25 + t25] : -1e30f;
            mx = fmaxf(mx, v[k]);
        }
        mx = fmaxf(mx, __shfl_xor(mx, 1, 64));
        mx = fmaxf(mx, __shfl_xor(mx, 2, 64));
        float ssum = 0.f;
        #pragma unroll
        for (int k = 0; k < 7; ++k) {
            int t25 = sub + k * 4;
            v[k] = (t25 < 25) ? __expf(v[k] - mx) : 0.f;
            ssum += v[k];
        }
        ssum += __shfl_xor(ssum, 1, 64);
        ssum += __shfl_xor(ssum, 2, 64);
        float rs = 1.f / ssum;
        #pragma unroll
        for (int k = 0; k < 7; ++k) {
            int t25 = sub + k * 4;
            if (t25 < 25) {
                int ti = t25 / 5, tj = t25 - ti * 5;
                int base = s * 8192 + wrow * 64
                         + ((((py + ti) ^ (wrow & 7)) << 3) | (pxl + tj));
                float kv = v[k] * rs;
                __hip_bfloat16 khi = __float2bfloat16(kv);
                whp[base] = khi;
                whp[base + 4096] = __float2bfloat16(kv - __bfloat162float(khi));
            }
        }
    }
    __syncthreads();

    // ---- phase E: out^T[c][pixg] per 4x4 subtile; 16 tasks (s,ch,pt) over 8 waves ----
    {
        #pragma unroll
        for (int rep = 0; rep < 2; ++rep) {
            int task = wave + rep * 8;
            int s = task >> 3, ch = (task >> 2) & 1, pt = task & 3;
            const __hip_bfloat16* wbase = whp + s * 8192;
            int wrow = pt * 16 + m;
            int s0 = ((q ^ (wrow & 7)) << 3);
            int s1 = (((4 + q) ^ (wrow & 7)) << 3);
            short8 bh0 = *(const short8*)(wbase + wrow * 64 + s0);
            short8 bl0 = *(const short8*)(wbase + 4096 + wrow * 64 + s0);
            short8 bh1 = *(const short8*)(wbase + wrow * 64 + s1);
            short8 bl1 = *(const short8*)(wbase + 4096 + wrow * 64 + s1);

            int pxm = m >> 2, gy = (m >> 1) & 1, gx = m & 1;
            size_t rowoff = (size_t)(2 * (ty0 + pt) + gy) * 128
                          + 2 * (tx0 + s * 4 + pxm) + gx;

            #pragma unroll
            for (int ct = 0; ct < 4; ++ct) {
                int ca = ch * 64 + ct * 16 + m;
                const __hip_bfloat16* xr = xsT + ca * XSTR + s * 4;
                union { short8 v; uint2 d[2]; } a0u, a1u;
                a0u.d[0] = *(const uint2*)(xr + q * 12);
                a0u.d[1] = *(const uint2*)(xr + q * 12 + 4);
                a1u.d[0] = *(const uint2*)(xr + (4 + q) * 12);
                a1u.d[1] = *(const uint2*)(xr + (4 + q) * 12 + 4);
                floatx4 acc;
                #pragma unroll
                for (int r = 0; r < 4; ++r) acc[r] = 0.f;
                acc = __builtin_amdgcn_mfma_f32_16x16x32_bf16(a0u.v, bh0, acc, 0, 0, 0);
                acc = __builtin_amdgcn_mfma_f32_16x16x32_bf16(a0u.v, bl0, acc, 0, 0, 0);
                acc = __builtin_amdgcn_mfma_f32_16x16x32_bf16(a1u.v, bh1, acc, 0, 0, 0);
                acc = __builtin_amdgcn_mfma_f32_16x16x32_bf16(a1u.v, bl1, acc, 0, 0, 0);
                int cbase = ch * 64 + ct * 16 + q * 4;
                #pragma unroll
                for (int r = 0; r < 4; ++r)
                    out[(((size_t)(b * 128 + cbase + r)) << 14) + rowoff] = acc[r];
            }
        }
    }
}

extern "C" void kernel_launch(void* const* d_in, const int* in_sizes, int n_in,
                              void* d_out, int out_size, void* d_ws, size_t ws_size,
                              hipStream_t stream) {
    const float* x     = (const float*)d_in[0];
    const float* w1    = (const float*)d_in[1];
    const float* w2    = (const float*)d_in[2];
    const float* gamma = (const float*)d_in[3];
    const float* beta  = (const float*)d_in[4];
    const float* mean  = (const float*)d_in[5];
    const float* var   = (const float*)d_in[6];
    float* out = (float*)d_out;
    char*  ws  = (char*)d_ws;

    prep_kernel<<<3621, 256, 0, stream>>>(x, w1, w2, gamma, beta, mean, var, ws);
    fused_carafe<<<512, 512, 0, stream>>>(ws, out);
}